// Round 17
// baseline (948.366 us; speedup 1.0000x reference)
//
#include <hip/hip_runtime.h>

typedef _Float16 half8 __attribute__((ext_vector_type(8)));
typedef float f32x4 __attribute__((ext_vector_type(4)));

#define NBLK 125
#define TOTBLK 250
#define GNNUNITS 528
#define BAR_INTS (8192 + GNNUNITS * 32)   // coop seq [0,8000) | gnn flags [8192, ...)

// ---------------- Kernel 1: fused spatial MLP (blocks 0-62) + tgi (blocks 63-158) ----------------
__global__ __launch_bounds__(256) void k_pre(
    const float* __restrict__ x, const float* __restrict__ x_mark,
    const float* __restrict__ sp_emb,
    const float* __restrict__ spW1, const float* __restrict__ spb1,
    const float* __restrict__ spW2, const float* __restrict__ spb2,
    const float* __restrict__ t_emb, const float* __restrict__ tWih,
    const float* __restrict__ tbih,
    _Float16* __restrict__ X, float* __restrict__ gi,
    int* __restrict__ seq, unsigned char* __restrict__ hA) {
  __shared__ __align__(16) unsigned char PSM[65152];
  int tid = threadIdx.x;
  if (blockIdx.x < 63) {
    float* W1s = (float*)PSM;
    float* W2s = (float*)(PSM + 16384);
    float* b1s = (float*)(PSM + 20480);
    float* b2s = (float*)(PSM + 20608);
    int gidx = blockIdx.x * 256 + tid;
    for (int i = gidx; i < BAR_INTS; i += 63 * 256) seq[i] = 0;
    for (int i = gidx; i < 4000; i += 63 * 256) ((unsigned int*)hA)[i] = 0u;
    for (int i = tid; i < 128 * 32; i += 256) W1s[i] = spW1[i];
    for (int i = tid; i < 32 * 32; i += 256) W2s[i] = spW2[i];
    if (tid < 32) { b1s[tid] = spb1[tid]; b2s[tid] = spb2[tid]; }
    __syncthreads();
    if (gidx >= 8 * 2000) return;
    int b = gidx / 2000, n = gidx % 2000;
    float h1[32];
#pragma unroll
    for (int l = 0; l < 32; l++) h1[l] = b1s[l];
    for (int k = 0; k < 96; k++) {
      float xv = x[((size_t)b * 96 + k) * 2000 + n];
#pragma unroll
      for (int l = 0; l < 32; l++) h1[l] = fmaf(xv, W1s[k * 32 + l], h1[l]);
    }
    for (int e4 = 0; e4 < 8; e4++) {
      float4 ev = *reinterpret_cast<const float4*>(&sp_emb[(size_t)n * 32 + e4 * 4]);
      float evs[4] = {ev.x, ev.y, ev.z, ev.w};
#pragma unroll
      for (int q = 0; q < 4; q++) {
        int e = e4 * 4 + q;
#pragma unroll
        for (int l = 0; l < 32; l++) h1[l] = fmaf(evs[q], W1s[(96 + e) * 32 + l], h1[l]);
      }
    }
    float out[32];
#pragma unroll
    for (int j = 0; j < 32; j++) out[j] = b2s[j];
    for (int l = 0; l < 32; l++) {
      float a = h1[l] > 0.0f ? h1[l] : (__expf(h1[l]) - 1.0f);
#pragma unroll
      for (int j = 0; j < 32; j++) out[j] = fmaf(a, W2s[l * 32 + j], out[j]);
    }
    _Float16* dst = X + ((size_t)b * 2096 + n) * 32;
#pragma unroll
    for (int j8 = 0; j8 < 4; j8++) {
      half8 v;
#pragma unroll
      for (int q = 0; q < 8; q++) v[q] = (_Float16)out[j8 * 8 + q];
      *reinterpret_cast<half8*>(dst + j8 * 8) = v;
    }
  } else {
    float (*xs)[2036] = (float(*)[2036])PSM;
    int row0 = (blockIdx.x - 63) * 8;
    for (int rr = 0; rr < 8; rr++) {
      int row = row0 + rr;
      int b = row / 96, t = row % 96;
      for (int k = tid; k < 2036; k += 256) {
        float v;
        if (k < 2000) v = x[((size_t)b * 96 + t) * 2000 + k];
        else if (k < 2004) v = x_mark[((size_t)b * 96 + t) * 4 + (k - 2000)];
        else v = t_emb[(size_t)t * 32 + (k - 2004)];
        xs[rr][k] = v;
      }
    }
    __syncthreads();
    for (int oi = tid; oi < 8 * 96; oi += 256) {
      int rr = oi & 7, g = oi >> 3;
      const float* w = tWih + (size_t)g * 2036;
      float acc = tbih[g];
      for (int k = 0; k < 2036; k += 4) {
        float4 wv = *reinterpret_cast<const float4*>(w + k);
        acc = fmaf(xs[rr][k + 0], wv.x, acc);
        acc = fmaf(xs[rr][k + 1], wv.y, acc);
        acc = fmaf(xs[rr][k + 2], wv.z, acc);
        acc = fmaf(xs[rr][k + 3], wv.w, acc);
      }
      gi[(size_t)(row0 + rr) * 96 + g] = acc;
    }
  }
}

// ---------------- Kernel 3: temporal GRU scan (hidden=32), f16 X out ----------------
__global__ __launch_bounds__(768) void k_tgru(
    const float* __restrict__ gi, const float* __restrict__ Whh,
    const float* __restrict__ bhh, _Float16* __restrict__ X) {
  __shared__ float Whs[96][33];
  __shared__ float hs[8][33];
  __shared__ float ga[3][8][33];
  int tid = threadIdx.x;
  for (int i = tid; i < 96 * 32; i += 768) Whs[i >> 5][i & 31] = Whh[i];
  if (tid < 256) hs[tid >> 5][tid & 31] = 0.0f;
  int g = tid >> 8, j = (tid >> 3) & 31, b = tid & 7;
  int row = g * 32 + j;
  float bb0 = 0.f, bb1 = 0.f, bb2 = 0.f;
  if (tid < 256) {
    int jj = tid & 31;
    bb0 = bhh[jj]; bb1 = bhh[32 + jj]; bb2 = bhh[64 + jj];
  }
  __syncthreads();
  for (int t = 0; t < 96; t++) {
    float acc = 0.0f;
#pragma unroll
    for (int k = 0; k < 32; k++) acc = fmaf(hs[b][k], Whs[row][k], acc);
    ga[g][b][j] = acc;
    __syncthreads();
    if (tid < 256) {
      int bb = tid >> 5, jj = tid & 31;
      const float* gp = gi + ((size_t)bb * 96 + t) * 96;
      float gr = ga[0][bb][jj] + bb0;
      float gz = ga[1][bb][jj] + bb1;
      float gn = ga[2][bb][jj] + bb2;
      float r = 1.0f / (1.0f + __expf(-(gp[jj] + gr)));
      float z = 1.0f / (1.0f + __expf(-(gp[32 + jj] + gz)));
      float n = tanhf(gp[64 + jj] + r * gn);
      float hn = (1.0f - z) * n + z * hs[bb][jj];
      hs[bb][jj] = hn;
      X[((size_t)bb * 2096 + 2000 + t) * 32 + jj] = (_Float16)hn;
    }
    __syncthreads();
  }
}

// ---------------- Kernel 4a: standalone GNN pass (fallback path, proven) ----------------
__global__ __launch_bounds__(256) void k_gnn(
    const _Float16* __restrict__ Xa, const _Float16* __restrict__ Xin,
    _Float16* __restrict__ Xout, const float* __restrict__ W,
    const float* __restrict__ bias) {
  __shared__ _Float16 XaR[32][40];
  __shared__ _Float16 Xm[2][64][40];
  __shared__ _Float16 Xq[2][64][42];
  __shared__ _Float16 At[32][72];
  __shared__ float Pm[32][36];
  __shared__ float Ws[32][36];
  __shared__ float bs[32];
  int tid = threadIdx.x;
  int l = tid & 63, w = tid >> 6;
  int b = blockIdx.y;
  int r0 = blockIdx.x * 32;
  const _Float16* Xab = Xa + (size_t)b * 2096 * 32;
  const _Float16* Xib = Xin + (size_t)b * 2096 * 32;
  half8 hz = {(_Float16)0, (_Float16)0, (_Float16)0, (_Float16)0,
              (_Float16)0, (_Float16)0, (_Float16)0, (_Float16)0};

  for (int i = tid; i < 1024; i += 256) Ws[i >> 5][i & 31] = W[i];
  if (tid < 32) bs[tid] = bias[tid];
  if (tid < 128) {
    int r = tid >> 2, k = (tid & 3) * 8;
    half8 v = (r0 + r < 2096)
                  ? *reinterpret_cast<const half8*>(Xab + (size_t)(r0 + r) * 32 + k)
                  : hz;
    *reinterpret_cast<half8*>(&XaR[r][k]) = v;
  }
  int sr = tid >> 2, sk = (tid & 3) * 8;
  {
    *reinterpret_cast<half8*>(&Xm[0][sr][sk]) =
        *reinterpret_cast<const half8*>(Xab + (size_t)sr * 32 + sk);
    half8 vq = *reinterpret_cast<const half8*>(Xib + (size_t)sr * 32 + sk);
    unsigned int u[4];
    __builtin_memcpy(u, &vq, 16);
    unsigned int* qp = (unsigned int*)&Xq[0][sr][sk];
    qp[0] = u[0]; qp[1] = u[1]; qp[2] = u[2]; qp[3] = u[3];
  }
  __syncthreads();

  int lr = l & 15, lk = (l >> 4) * 8, lq = (l >> 4) * 4;
  int smt = w >> 1, snt2 = w & 1;
  int pmt = w >> 1, pnt = w & 1;
  half8 afrag = *reinterpret_cast<const half8*>(&XaR[smt * 16 + lr][lk]);
  f32x4 pacc = {0.f, 0.f, 0.f, 0.f};

  for (int tt = 0; tt < 33; tt++) {
    int cur = tt & 1, nb = cur ^ 1;
    half8 vm = hz, vq = hz;
    bool hv = (tt + 1 < 33);
    if (hv) {
      int gm = (tt + 1) * 64 + sr;
      if (gm < 2096) {
        vm = *reinterpret_cast<const half8*>(Xab + (size_t)gm * 32 + sk);
        vq = *reinterpret_cast<const half8*>(Xib + (size_t)gm * 32 + sk);
      }
    }
#pragma unroll
    for (int n16 = 0; n16 < 2; n16++) {
      int c0 = snt2 * 32 + n16 * 16;
      half8 bfrag = *reinterpret_cast<const half8*>(&Xm[cur][c0 + lr][lk]);
      f32x4 s4 = __builtin_amdgcn_mfma_f32_16x16x32_f16(
          afrag, bfrag, (f32x4){0.f, 0.f, 0.f, 0.f}, 0, 0, 0);
#pragma unroll
      for (int j = 0; j < 4; j++) {
        float e = __expf(-2.0f * fmaxf(s4[j], 0.0f));
        At[smt * 16 + lq + j][c0 + lr] = (_Float16)((1.0f - e) / (1.0f + e));
      }
    }
    __syncthreads();
    {
      int nn = pnt * 16 + lr;
#pragma unroll
      for (int kc = 0; kc < 2; kc++) {
        half8 af = *reinterpret_cast<const half8*>(&At[pmt * 16 + lr][kc * 32 + lk]);
        half8 bf;
        int kb = kc * 32 + lk;
#pragma unroll
        for (int e = 0; e < 8; e++) bf[e] = Xq[cur][kb + e][nn];
        pacc = __builtin_amdgcn_mfma_f32_16x16x32_f16(af, bf, pacc, 0, 0, 0);
      }
    }
    if (hv) {
      *reinterpret_cast<half8*>(&Xm[nb][sr][sk]) = vm;
      unsigned int u[4];
      __builtin_memcpy(u, &vq, 16);
      unsigned int* qp = (unsigned int*)&Xq[nb][sr][sk];
      qp[0] = u[0]; qp[1] = u[1]; qp[2] = u[2]; qp[3] = u[3];
    }
    __syncthreads();
  }

#pragma unroll
  for (int j = 0; j < 4; j++) Pm[pmt * 16 + lq + j][pnt * 16 + lr] = pacc[j];
  __syncthreads();
  int r = tid & 31, fgr = tid >> 5;
  int f0 = fgr * 4;
  float o[4];
#pragma unroll
  for (int j = 0; j < 4; j++) o[j] = bs[f0 + j];
#pragma unroll
  for (int k = 0; k < 32; k++) {
    float mv = Pm[r][k];
    float4 wv = *reinterpret_cast<const float4*>(&Ws[k][f0]);
    o[0] = fmaf(mv, wv.x, o[0]);
    o[1] = fmaf(mv, wv.y, o[1]);
    o[2] = fmaf(mv, wv.z, o[2]);
    o[3] = fmaf(mv, wv.w, o[3]);
  }
  int grr = r0 + r;
  if (grr < 2096) {
    _Float16* dst = Xout + ((size_t)b * 2096 + grr) * 32 + f0;
#pragma unroll
    for (int j = 0; j < 4; j++) {
      float v = o[j];
      dst[j] = (_Float16)(v > 0.0f ? v : (__expf(v) - 1.0f));
    }
  }
}

// ---------------- Kernel 4b: cooperative fused 4-pass GNN (528 x 256, VGPR-capped) ----------------
// __launch_bounds__(256,4): forces VGPR <= 128 -> 4 blocks/CU -> 1024 coop capacity >= 528.
__global__ __launch_bounds__(256, 4) void k_gnnmega(
    _Float16* __restrict__ X0, _Float16* __restrict__ X1, _Float16* __restrict__ X2,
    const float* __restrict__ gcnW, const float* __restrict__ gcnb,
    int* __restrict__ seqbase) {
  __shared__ _Float16 XaR[32][40];
  __shared__ _Float16 Xm[2][64][40];
  __shared__ _Float16 Xq[2][64][42];
  __shared__ _Float16 At[32][72];
  __shared__ float Pm[32][36];
  __shared__ float Ws[32][36];
  __shared__ float bs[32];
  int tid = threadIdx.x;
  int blk = blockIdx.x;
  int* gflags = seqbase + 8192;

  const _Float16* gXa[4] = {X0, X0, X2, X2};
  const _Float16* gXi[4] = {X0, X1, X2, X0};
  _Float16* gXo[4] = {X1, X2, X0, X1};
  half8 hz = {(_Float16)0, (_Float16)0, (_Float16)0, (_Float16)0,
              (_Float16)0, (_Float16)0, (_Float16)0, (_Float16)0};

  int ub = blk / 66, ux = blk % 66;
  int r0 = ux * 32;
  int l = tid & 63, w = tid >> 6;
  int lr = l & 15, lk = (l >> 4) * 8, lq = (l >> 4) * 4;
  int smt = w >> 1, snt2 = w & 1;
  int pmt = w >> 1, pnt = w & 1;
  int sr = tid >> 2, sk = (tid & 3) * 8;

  for (int p = 0; p < 4; p++) {
    const _Float16* Xab = gXa[p] + (size_t)ub * 2096 * 32;
    const _Float16* Xib = gXi[p] + (size_t)ub * 2096 * 32;
    _Float16* Xob = gXo[p] + (size_t)ub * 2096 * 32;
    const float* W = gcnW + p * 1024;
    const float* bias = gcnb + p * 32;

    for (int i = tid; i < 1024; i += 256) Ws[i >> 5][i & 31] = W[i];
    if (tid < 32) bs[tid] = bias[tid];
    if (tid < 128) {
      int r = tid >> 2, k = (tid & 3) * 8;
      half8 v = (r0 + r < 2096)
                    ? *reinterpret_cast<const half8*>(Xab + (size_t)(r0 + r) * 32 + k)
                    : hz;
      *reinterpret_cast<half8*>(&XaR[r][k]) = v;
    }
    {
      *reinterpret_cast<half8*>(&Xm[0][sr][sk]) =
          *reinterpret_cast<const half8*>(Xab + (size_t)sr * 32 + sk);
      half8 vq = *reinterpret_cast<const half8*>(Xib + (size_t)sr * 32 + sk);
      unsigned int u[4];
      __builtin_memcpy(u, &vq, 16);
      unsigned int* qp = (unsigned int*)&Xq[0][sr][sk];
      qp[0] = u[0]; qp[1] = u[1]; qp[2] = u[2]; qp[3] = u[3];
    }
    __syncthreads();

    half8 afrag = *reinterpret_cast<const half8*>(&XaR[smt * 16 + lr][lk]);
    f32x4 pacc = {0.f, 0.f, 0.f, 0.f};

    for (int tt = 0; tt < 33; tt++) {
      int cur = tt & 1, nb = cur ^ 1;
      half8 vm = hz, vq = hz;
      bool hv = (tt + 1 < 33);
      if (hv) {
        int gm = (tt + 1) * 64 + sr;
        if (gm < 2096) {
          vm = *reinterpret_cast<const half8*>(Xab + (size_t)gm * 32 + sk);
          vq = *reinterpret_cast<const half8*>(Xib + (size_t)gm * 32 + sk);
        }
      }
#pragma unroll
      for (int n16 = 0; n16 < 2; n16++) {
        int c0 = snt2 * 32 + n16 * 16;
        half8 bfrag = *reinterpret_cast<const half8*>(&Xm[cur][c0 + lr][lk]);
        f32x4 s4 = __builtin_amdgcn_mfma_f32_16x16x32_f16(
            afrag, bfrag, (f32x4){0.f, 0.f, 0.f, 0.f}, 0, 0, 0);
#pragma unroll
        for (int j = 0; j < 4; j++) {
          float e = __expf(-2.0f * fmaxf(s4[j], 0.0f));
          At[smt * 16 + lq + j][c0 + lr] = (_Float16)((1.0f - e) / (1.0f + e));
        }
      }
      __syncthreads();
      {
        int nn = pnt * 16 + lr;
#pragma unroll
        for (int kc = 0; kc < 2; kc++) {
          half8 af = *reinterpret_cast<const half8*>(&At[pmt * 16 + lr][kc * 32 + lk]);
          half8 bf;
          int kb = kc * 32 + lk;
#pragma unroll
          for (int e = 0; e < 8; e++) bf[e] = Xq[cur][kb + e][nn];
          pacc = __builtin_amdgcn_mfma_f32_16x16x32_f16(af, bf, pacc, 0, 0, 0);
        }
      }
      if (hv) {
        *reinterpret_cast<half8*>(&Xm[nb][sr][sk]) = vm;
        unsigned int u[4];
        __builtin_memcpy(u, &vq, 16);
        unsigned int* qp = (unsigned int*)&Xq[nb][sr][sk];
        qp[0] = u[0]; qp[1] = u[1]; qp[2] = u[2]; qp[3] = u[3];
      }
      __syncthreads();
    }

#pragma unroll
    for (int j = 0; j < 4; j++) Pm[pmt * 16 + lq + j][pnt * 16 + lr] = pacc[j];
    __syncthreads();
    {
      int r = tid & 31, fgr = tid >> 5;
      int f0 = fgr * 4;
      float o[4];
#pragma unroll
      for (int j = 0; j < 4; j++) o[j] = bs[f0 + j];
#pragma unroll
      for (int k = 0; k < 32; k++) {
        float mv = Pm[r][k];
        float4 wv = *reinterpret_cast<const float4*>(&Ws[k][f0]);
        o[0] = fmaf(mv, wv.x, o[0]);
        o[1] = fmaf(mv, wv.y, o[1]);
        o[2] = fmaf(mv, wv.z, o[2]);
        o[3] = fmaf(mv, wv.w, o[3]);
      }
      int grr = r0 + r;
      if (grr < 2096) {
#pragma unroll
        for (int j = 0; j < 4; j++) {
          float v = o[j];
          o[j] = v > 0.0f ? v : (__expf(v) - 1.0f);
        }
        _Float16 h0 = (_Float16)o[0], h1v = (_Float16)o[1];
        _Float16 h2 = (_Float16)o[2], h3 = (_Float16)o[3];
        unsigned short u0, u1, u2, u3;
        __builtin_memcpy(&u0, &h0, 2); __builtin_memcpy(&u1, &h1v, 2);
        __builtin_memcpy(&u2, &h2, 2); __builtin_memcpy(&u3, &h3, 2);
        unsigned int* dst = (unsigned int*)(Xob + (size_t)grr * 32 + f0);
        __hip_atomic_store(dst, ((unsigned int)u1 << 16) | u0, __ATOMIC_RELAXED,
                           __HIP_MEMORY_SCOPE_AGENT);
        __hip_atomic_store(dst + 1, ((unsigned int)u3 << 16) | u2, __ATOMIC_RELAXED,
                           __HIP_MEMORY_SCOPE_AGENT);
      }
    }
    __syncthreads();  // drains this block's write-through stores
    if (p < 3) {
      if (tid == 0)
        __hip_atomic_store(&gflags[blk * 32], p + 1, __ATOMIC_RELAXED,
                           __HIP_MEMORY_SCOPE_AGENT);
      if (tid < 64) {
        while (true) {
          bool ok = true;
#pragma unroll
          for (int q = 0; q < 9; q++) {
            int idx = tid + 64 * q;
            if (idx < GNNUNITS) {
              int v = __hip_atomic_load(&gflags[idx * 32], __ATOMIC_RELAXED,
                                        __HIP_MEMORY_SCOPE_AGENT);
              if (v < p + 1) ok = false;
            }
          }
          if (__all(ok)) break;
          __builtin_amdgcn_s_sleep(2);
        }
        if (tid == 0)
          (void)__hip_atomic_load(&gflags[0], __ATOMIC_ACQUIRE,
                                  __HIP_MEMORY_SCOPE_AGENT);
      }
      __syncthreads();
    }
  }
}

// ---------------- Kernel 7: fused persistent kernel (GRU + rs + final combine) ----------------
__global__ __launch_bounds__(1024) void k_trgru(
    const _Float16* __restrict__ X, const float* __restrict__ wih,
    const float* __restrict__ bih, float* __restrict__ gi,
    const float* __restrict__ whh, const float* __restrict__ bhh,
    unsigned char* __restrict__ hA, unsigned char* __restrict__ hB,
    float* __restrict__ rt, int* __restrict__ seq,
    const float* __restrict__ frW1, const float* __restrict__ frb1,
    const float* __restrict__ frW2, const float* __restrict__ frb2,
    float* __restrict__ rs, const float* __restrict__ outW,
    const float* __restrict__ outb, float* __restrict__ out) {
  __shared__ __align__(16) unsigned char SM[122880];
  int tid = threadIdx.x;
  int blk = blockIdx.x;

  if (blk >= NBLK) {
    float* W1s = (float*)(SM);
    float* W2s = (float*)(SM + 12288);
    float* b1s = (float*)(SM + 50688);
    float* b2s = (float*)(SM + 51072);
    float* Xt  = (float*)(SM + 51456);
    float* Hl  = (float*)(SM + 55680);
    for (int i = tid; i < 32 * 96; i += 1024) W1s[i] = frW1[i];
    for (int i = tid; i < 96 * 96; i += 1024) W2s[(i / 96) * 100 + (i % 96)] = frW2[i];
    if (tid < 96) { b1s[tid] = frb1[tid]; b2s[tid] = frb2[tid]; }
    __syncthreads();
    for (int ti = blk - NBLK; ti < 504; ti += NBLK) {
      int b = ti / 63, n0 = (ti % 63) * 32;
      {
        int r = tid >> 5, k = tid & 31;
        Xt[r * 33 + k] =
            (n0 + r < 2000) ? (float)X[((size_t)b * 2096 + n0 + r) * 32 + k] : 0.0f;
      }
      __syncthreads();
#pragma unroll
      for (int q = 0; q < 3; q++) {
        int idx = q * 1024 + tid;
        int r = idx / 96, c = idx % 96;
        float a = b1s[c];
#pragma unroll 8
        for (int k = 0; k < 32; k++) a = fmaf(Xt[r * 33 + k], W1s[k * 96 + c], a);
        Hl[r * 100 + c] = a > 0.0f ? a : (__expf(a) - 1.0f);
      }
      __syncthreads();
#pragma unroll
      for (int q = 0; q < 3; q++) {
        int idx = q * 1024 + tid;
        int r = idx / 96, c = idx % 96;
        float o = b2s[c];
#pragma unroll 8
        for (int k = 0; k < 96; k++) o = fmaf(Hl[r * 100 + k], W2s[k * 100 + c], o);
        if (n0 + r < 2000) {
          __hip_atomic_store(&rs[((size_t)b * 2000 + n0 + r) * 96 + c], o,
                             __ATOMIC_RELAXED, __HIP_MEMORY_SCOPE_AGENT);
        }
      }
      __syncthreads();
    }
    if (tid == 0) {
      __hip_atomic_store(&seq[blk * 32], 96, __ATOMIC_RELAXED,
                         __HIP_MEMORY_SCOPE_AGENT);
    }
  } else {
    unsigned char* wf = SM;               // 3*32768
    float* pt = (float*)(SM + 98304);     // 6144 f32
    int l = tid & 63, w = tid >> 6;

    for (int i = tid; i < 12288; i += 1024) ((unsigned long long*)wf)[i] = 0ull;

    if (tid < 768) {
      int t = tid >> 3, b = tid & 7;
      float xr[32];
      const _Float16* xp = X + ((size_t)b * 2096 + 2000 + t) * 32;
#pragma unroll
      for (int k = 0; k < 32; k++) xr[k] = (float)xp[k];
      float* gp = gi + ((size_t)b * 96 + t) * 6000;
      for (int g = 0; g < 3; g++) {
#pragma unroll
        for (int j = 0; j < 16; j++) {
          int row = g * 2000 + blk * 16 + j;
          const float* wr = wih + (size_t)row * 32;
          float a = bih[row];
#pragma unroll 8
          for (int k = 0; k < 32; k++) a = fmaf(xr[k], wr[k], a);
          gp[row] = a;
        }
      }
    }

    for (int i = tid; i < 3 * 64 * 64; i += 1024) {
      int g = i >> 12;
      int c = (i >> 6) & 63;
      int l2 = i & 63;
      int j = l2 & 15;
      int k0 = c * 32 + ((l2 >> 4) << 3);
      if (k0 <= 1992) {
        const float* src = whh + ((size_t)(g * 2000 + blk * 16 + j)) * 2000 + k0;
        float4 v0 = *reinterpret_cast<const float4*>(src);
        float4 v1 = *reinterpret_cast<const float4*>(src + 4);
        unsigned int lo = __builtin_amdgcn_cvt_pk_fp8_f32(v0.x, v0.y, 0, false);
        lo = __builtin_amdgcn_cvt_pk_fp8_f32(v0.z, v0.w, lo, true);
        unsigned int hi = __builtin_amdgcn_cvt_pk_fp8_f32(v1.x, v1.y, 0, false);
        hi = __builtin_amdgcn_cvt_pk_fp8_f32(v1.z, v1.w, hi, true);
        unsigned long long q = ((unsigned long long)hi << 32) | (unsigned long long)lo;
        *reinterpret_cast<unsigned long long*>(wf + (size_t)g * 32768 + c * 512 + l2 * 8) = q;
      }
    }

    int cj = tid >> 3, cb = tid & 7;
    int jg = blk * 16 + cj;
    float hold = 0.0f, bR = 0.f, bZ = 0.f, bN = 0.f;
    if (tid < 128) {
      bR = bhh[jg]; bZ = bhh[2000 + jg]; bN = bhh[4000 + jg];
    }
    int bb = l & 7, kblk = (l >> 4) * 8;
    __syncthreads();

    float gir = 0.f, giz = 0.f, gin = 0.f;
    if (tid < 128) {
      const float* gp = gi + ((size_t)cb * 96 + 0) * 6000;
      gir = gp[jg]; giz = gp[2000 + jg]; gin = gp[4000 + jg];
    }

    for (int t = 0; t < 96; t++) {
      const unsigned char* hc = (t & 1) ? hB : hA;
      unsigned char* hn = (t & 1) ? hA : hB;
      f32x4 a0 = {0.f, 0.f, 0.f, 0.f}, a1 = {0.f, 0.f, 0.f, 0.f}, a2 = {0.f, 0.f, 0.f, 0.f};
#pragma unroll
      for (int i = 0; i < 4; i++) {
        int c = w * 4 + i;
        int k0 = c * 32 + kblk;
        long long bv = 0;
        if (k0 <= 1992)
          bv = *reinterpret_cast<const long long*>(hc + bb * 2000 + k0);
        long long w0 = *reinterpret_cast<const long long*>(wf + 0 * 32768 + c * 512 + l * 8);
        long long w1 = *reinterpret_cast<const long long*>(wf + 1 * 32768 + c * 512 + l * 8);
        long long w2 = *reinterpret_cast<const long long*>(wf + 2 * 32768 + c * 512 + l * 8);
        a0 = __builtin_amdgcn_mfma_f32_16x16x32_fp8_fp8(w0, bv, a0, 0, 0, 0);
        a1 = __builtin_amdgcn_mfma_f32_16x16x32_fp8_fp8(w1, bv, a1, 0, 0, 0);
        a2 = __builtin_amdgcn_mfma_f32_16x16x32_fp8_fp8(w2, bv, a2, 0, 0, 0);
      }
      {
        int bcol = l & 15;
        if (bcol < 8) {
          int lb = l >> 4;
          *reinterpret_cast<f32x4*>(pt + w * 384 + 0 * 128 + lb * 32 + bcol * 4) = a0;
          *reinterpret_cast<f32x4*>(pt + w * 384 + 1 * 128 + lb * 32 + bcol * 4) = a1;
          *reinterpret_cast<f32x4*>(pt + w * 384 + 2 * 128 + lb * 32 + bcol * 4) = a2;
        }
      }
      __syncthreads();
      if (tid < 128) {
        float s[3];
#pragma unroll
        for (int g = 0; g < 3; g++) {
          int base = g * 128 + (cj >> 2) * 32 + cb * 4 + (cj & 3);
          float acc = 0.f;
#pragma unroll
          for (int w2 = 0; w2 < 16; w2++) acc += pt[w2 * 384 + base];
          s[g] = acc;
        }
        float r_ = 1.0f / (1.0f + __expf(-(gir + s[0] + bR)));
        float z_ = 1.0f / (1.0f + __expf(-(giz + s[1] + bZ)));
        float n_ = tanhf(gin + r_ * (s[2] + bN));
        hold = (1.0f - z_) * n_ + z_ * hold;
        {
          unsigned int p = __builtin_amdgcn_cvt_pk_fp8_f32(hold, 0.0f, 0, false);
          __hip_atomic_store(hn + cb * 2000 + jg, (unsigned char)(p & 0xFF),
                             __ATOMIC_RELAXED, __HIP_MEMORY_SCOPE_AGENT);
        }
        __hip_atomic_store(&rt[((size_t)cb * 96 + t) * 2000 + jg], hold,
                           __ATOMIC_RELAXED, __HIP_MEMORY_SCOPE_AGENT);
      }
      __syncthreads();
      if (tid == 0) {
        __hip_atomic_store(&seq[blk * 32], t + 1, __ATOMIC_RELAXED,
                           __HIP_MEMORY_SCOPE_AGENT);
      }
      if (tid < 128 && t + 1 < 96) {
        const float* gp = gi + ((size_t)cb * 96 + (t + 1)) * 6000;
        gir = gp[jg]; giz = gp[2000 + jg]; gin = gp[4000 + jg];
      }
      if ((tid >> 6) == 2) {
        int lane = tid & 63;
        const int* s1 = &seq[lane * 32];
        const int* s2 = &seq[((lane + 64) < NBLK ? (lane + 64) : lane) * 32];
        while (true) {
          int v1 = __hip_atomic_load(s1, __ATOMIC_RELAXED, __HIP_MEMORY_SCOPE_AGENT);
          int v2 = __hip_atomic_load(s2, __ATOMIC_RELAXED, __HIP_MEMORY_SCOPE_AGENT);
          if (__all(v1 > t && v2 > t)) break;
          __builtin_amdgcn_s_sleep(1);
        }
        if (lane == 0) {
          (void)__hip_atomic_load(s1, __ATOMIC_ACQUIRE, __HIP_MEMORY_SCOPE_AGENT);
        }
      }
      __syncthreads();
    }
  }

  // shared epilogue: final barrier + out matmul
  {
    float* wsm = (float*)SM;
    __syncthreads();
    if (tid >= 128 && tid < 224) wsm[tid - 128] = outW[tid - 128];
    if (tid == 224) wsm[96] = outb[0];
    if (tid < 64) {
      const int* p0 = &seq[tid * 32];
      const int* p1 = &seq[(tid + 64) * 32];
      const int* p2 = &seq[(tid + 128) * 32];
      int i3 = tid + 192; if (i3 >= TOTBLK) i3 = tid;
      const int* p3 = &seq[i3 * 32];
      while (true) {
        int v0 = __hip_atomic_load(p0, __ATOMIC_RELAXED, __HIP_MEMORY_SCOPE_AGENT);
        int v1 = __hip_atomic_load(p1, __ATOMIC_RELAXED, __HIP_MEMORY_SCOPE_AGENT);
        int v2 = __hip_atomic_load(p2, __ATOMIC_RELAXED, __HIP_MEMORY_SCOPE_AGENT);
        int v3 = __hip_atomic_load(p3, __ATOMIC_RELAXED, __HIP_MEMORY_SCOPE_AGENT);
        if (__all(v0 >= 96 && v1 >= 96 && v2 >= 96 && v3 >= 96)) break;
        __builtin_amdgcn_s_sleep(2);
      }
      if (tid == 0) {
        (void)__hip_atomic_load(p0, __ATOMIC_ACQUIRE, __HIP_MEMORY_SCOPE_AGENT);
      }
    }
    __syncthreads();
    if (tid < 64) {
      int idx = blk * 64 + tid;
      int b = idx / 2000, n = idx % 2000;
      const float* rsp = rs + (size_t)idx * 96;
      float acc = wsm[96];
      for (int t4 = 0; t4 < 24; t4++) {
        float4 rv = *reinterpret_cast<const float4*>(rsp + t4 * 4);
        int t = t4 * 4;
        acc = fmaf(rv.x + rt[((size_t)b * 96 + t + 0) * 2000 + n], wsm[t + 0], acc);
        acc = fmaf(rv.y + rt[((size_t)b * 96 + t + 1) * 2000 + n], wsm[t + 1], acc);
        acc = fmaf(rv.z + rt[((size_t)b * 96 + t + 2) * 2000 + n], wsm[t + 2], acc);
        acc = fmaf(rv.w + rt[((size_t)b * 96 + t + 3) * 2000 + n], wsm[t + 3], acc);
      }
      out[idx] = acc;
    }
  }
}

extern "C" void kernel_launch(void* const* d_in, const int* in_sizes, int n_in,
                              void* d_out, int out_size, void* d_ws, size_t ws_size,
                              hipStream_t stream) {
  const float* x      = (const float*)d_in[0];
  const float* x_mark = (const float*)d_in[1];
  const float* sp_emb = (const float*)d_in[2];
  const float* sp_W1  = (const float*)d_in[3];
  const float* sp_b1  = (const float*)d_in[4];
  const float* sp_W2  = (const float*)d_in[5];
  const float* sp_b2  = (const float*)d_in[6];
  const float* t_emb  = (const float*)d_in[7];
  const float* t_Wih  = (const float*)d_in[8];
  const float* t_Whh  = (const float*)d_in[9];
  const float* t_bih  = (const float*)d_in[10];
  const float* t_bhh  = (const float*)d_in[11];
  const float* gcn_W  = (const float*)d_in[12];
  const float* gcn_b  = (const float*)d_in[13];
  const float* fr_W1  = (const float*)d_in[14];
  const float* fr_b1  = (const float*)d_in[15];
  const float* fr_W2  = (const float*)d_in[16];
  const float* fr_b2  = (const float*)d_in[17];
  const float* tr_Wih = (const float*)d_in[18];
  const float* tr_Whh = (const float*)d_in[19];
  const float* tr_bih = (const float*)d_in[20];
  const float* tr_bhh = (const float*)d_in[21];
  const float* out_W  = (const float*)d_in[22];
  const float* out_b  = (const float*)d_in[23];
  (void)in_sizes; (void)n_in; (void)out_size; (void)ws_size;

  float* ws = (float*)d_ws;
  float* X0   = ws;
  float* X1   = X0 + 536576;
  float* X2   = X1 + 536576;
  float* tgi  = X2 + 536576;           // 768*96
  float* trgi = tgi + 73728;           // 8*96*6000
  float* hsl  = trgi + 4608000;        // hA/hB (fp8, 16000 B each)
  float* rt   = hsl + 16000;           // 8*96*2000
  float* rs   = rt + 1536000;          // 8*2000*96
  float* barf = rs + 1536000;          // BAR_INTS ints (seq + gnn flags)

  _Float16* X0h = (_Float16*)X0;
  _Float16* X1h = (_Float16*)X1;
  _Float16* X2h = (_Float16*)X2;
  unsigned char* hA = (unsigned char*)hsl;
  unsigned char* hB = hA + 16000;
  int* seq = (int*)barf;

  k_pre<<<159, 256, 0, stream>>>(x, x_mark, sp_emb, sp_W1, sp_b1, sp_W2, sp_b2,
                                 t_emb, t_Wih, t_bih, X0h, tgi, seq, hA);
  k_tgru<<<1, 768, 0, stream>>>(tgi, t_Whh, t_bhh, X0h);

  {
    // attempt fused cooperative GNN; on rejection fall back to 4 standalone passes
    _Float16* a0 = X0h; _Float16* a1 = X1h; _Float16* a2 = X2h;
    const float* a3 = gcn_W;
    const float* a4 = gcn_b;
    int* a5 = seq;
    void* cargs[] = {&a0, &a1, &a2, &a3, &a4, &a5};
    hipError_t e = hipLaunchCooperativeKernel((const void*)k_gnnmega, dim3(GNNUNITS),
                                              dim3(256), cargs, 0, stream);
    if (e != hipSuccess) {
      (void)hipGetLastError();  // clear sticky error
      dim3 gg(66, 8);
      k_gnn<<<gg, 256, 0, stream>>>(X0h, X0h, X1h, gcn_W + 0 * 1024, gcn_b + 0 * 32);
      k_gnn<<<gg, 256, 0, stream>>>(X0h, X1h, X2h, gcn_W + 1 * 1024, gcn_b + 1 * 32);
      k_gnn<<<gg, 256, 0, stream>>>(X2h, X2h, X0h, gcn_W + 2 * 1024, gcn_b + 2 * 32);
      k_gnn<<<gg, 256, 0, stream>>>(X2h, X0h, X1h, gcn_W + 3 * 1024, gcn_b + 3 * 32);
    }
  }

  {
    const _Float16* a0 = X1h;
    const float* a1 = tr_Wih;
    const float* a2 = tr_bih;
    float* a3 = trgi;
    const float* a4 = tr_Whh;
    const float* a5 = tr_bhh;
    unsigned char* a6 = hA;
    unsigned char* a7 = hB;
    float* a8 = rt;
    int* a9 = seq;
    const float* a10 = fr_W1;
    const float* a11 = fr_b1;
    const float* a12 = fr_W2;
    const float* a13 = fr_b2;
    float* a14 = rs;
    const float* a15 = out_W;
    const float* a16 = out_b;
    float* a17 = (float*)d_out;
    void* cargs[] = {&a0, &a1, &a2, &a3, &a4, &a5, &a6, &a7, &a8, &a9,
                     &a10, &a11, &a12, &a13, &a14, &a15, &a16, &a17};
    hipLaunchCooperativeKernel((const void*)k_trgru, dim3(TOTBLK), dim3(1024), cargs, 0, stream);
  }
}

// Round 18
// 907.800 us; speedup vs baseline: 1.0447x; 1.0447x over previous
//
#include <hip/hip_runtime.h>

typedef _Float16 half8 __attribute__((ext_vector_type(8)));
typedef float f32x4 __attribute__((ext_vector_type(4)));

#define NBLK 125
#define TOTBLK 250
#define BAR_INTS (TOTBLK * 32)

// ---------------- Kernel 1: fused spatial MLP (blocks 0-62) + tgi (blocks 63-158) ----------------
__global__ __launch_bounds__(256) void k_pre(
    const float* __restrict__ x, const float* __restrict__ x_mark,
    const float* __restrict__ sp_emb,
    const float* __restrict__ spW1, const float* __restrict__ spb1,
    const float* __restrict__ spW2, const float* __restrict__ spb2,
    const float* __restrict__ t_emb, const float* __restrict__ tWih,
    const float* __restrict__ tbih,
    _Float16* __restrict__ X, float* __restrict__ gi,
    int* __restrict__ seq, unsigned char* __restrict__ hA) {
  __shared__ __align__(16) unsigned char PSM[65152];
  int tid = threadIdx.x;
  if (blockIdx.x < 63) {
    float* W1s = (float*)PSM;
    float* W2s = (float*)(PSM + 16384);
    float* b1s = (float*)(PSM + 20480);
    float* b2s = (float*)(PSM + 20608);
    int gidx = blockIdx.x * 256 + tid;
    for (int i = gidx; i < BAR_INTS; i += 63 * 256) seq[i] = 0;
    for (int i = gidx; i < 4000; i += 63 * 256) ((unsigned int*)hA)[i] = 0u;
    for (int i = tid; i < 128 * 32; i += 256) W1s[i] = spW1[i];
    for (int i = tid; i < 32 * 32; i += 256) W2s[i] = spW2[i];
    if (tid < 32) { b1s[tid] = spb1[tid]; b2s[tid] = spb2[tid]; }
    __syncthreads();
    if (gidx >= 8 * 2000) return;
    int b = gidx / 2000, n = gidx % 2000;
    float h1[32];
#pragma unroll
    for (int l = 0; l < 32; l++) h1[l] = b1s[l];
    for (int k = 0; k < 96; k++) {
      float xv = x[((size_t)b * 96 + k) * 2000 + n];
#pragma unroll
      for (int l = 0; l < 32; l++) h1[l] = fmaf(xv, W1s[k * 32 + l], h1[l]);
    }
    for (int e4 = 0; e4 < 8; e4++) {
      float4 ev = *reinterpret_cast<const float4*>(&sp_emb[(size_t)n * 32 + e4 * 4]);
      float evs[4] = {ev.x, ev.y, ev.z, ev.w};
#pragma unroll
      for (int q = 0; q < 4; q++) {
        int e = e4 * 4 + q;
#pragma unroll
        for (int l = 0; l < 32; l++) h1[l] = fmaf(evs[q], W1s[(96 + e) * 32 + l], h1[l]);
      }
    }
    float out[32];
#pragma unroll
    for (int j = 0; j < 32; j++) out[j] = b2s[j];
    for (int l = 0; l < 32; l++) {
      float a = h1[l] > 0.0f ? h1[l] : (__expf(h1[l]) - 1.0f);
#pragma unroll
      for (int j = 0; j < 32; j++) out[j] = fmaf(a, W2s[l * 32 + j], out[j]);
    }
    _Float16* dst = X + ((size_t)b * 2096 + n) * 32;
#pragma unroll
    for (int j8 = 0; j8 < 4; j8++) {
      half8 v;
#pragma unroll
      for (int q = 0; q < 8; q++) v[q] = (_Float16)out[j8 * 8 + q];
      *reinterpret_cast<half8*>(dst + j8 * 8) = v;
    }
  } else {
    float (*xs)[2036] = (float(*)[2036])PSM;
    int row0 = (blockIdx.x - 63) * 8;
    for (int rr = 0; rr < 8; rr++) {
      int row = row0 + rr;
      int b = row / 96, t = row % 96;
      for (int k = tid; k < 2036; k += 256) {
        float v;
        if (k < 2000) v = x[((size_t)b * 96 + t) * 2000 + k];
        else if (k < 2004) v = x_mark[((size_t)b * 96 + t) * 4 + (k - 2000)];
        else v = t_emb[(size_t)t * 32 + (k - 2004)];
        xs[rr][k] = v;
      }
    }
    __syncthreads();
    for (int oi = tid; oi < 8 * 96; oi += 256) {
      int rr = oi & 7, g = oi >> 3;
      const float* w = tWih + (size_t)g * 2036;
      float acc = tbih[g];
      for (int k = 0; k < 2036; k += 4) {
        float4 wv = *reinterpret_cast<const float4*>(w + k);
        acc = fmaf(xs[rr][k + 0], wv.x, acc);
        acc = fmaf(xs[rr][k + 1], wv.y, acc);
        acc = fmaf(xs[rr][k + 2], wv.z, acc);
        acc = fmaf(xs[rr][k + 3], wv.w, acc);
      }
      gi[(size_t)(row0 + rr) * 96 + g] = acc;
    }
  }
}

// ---------------- Kernel 3: temporal GRU scan (hidden=32), f16 X out ----------------
__global__ __launch_bounds__(768) void k_tgru(
    const float* __restrict__ gi, const float* __restrict__ Whh,
    const float* __restrict__ bhh, _Float16* __restrict__ X) {
  __shared__ float Whs[96][33];
  __shared__ float hs[8][33];
  __shared__ float ga[3][8][33];
  int tid = threadIdx.x;
  for (int i = tid; i < 96 * 32; i += 768) Whs[i >> 5][i & 31] = Whh[i];
  if (tid < 256) hs[tid >> 5][tid & 31] = 0.0f;
  int g = tid >> 8, j = (tid >> 3) & 31, b = tid & 7;
  int row = g * 32 + j;
  float bb0 = 0.f, bb1 = 0.f, bb2 = 0.f;
  if (tid < 256) {
    int jj = tid & 31;
    bb0 = bhh[jj]; bb1 = bhh[32 + jj]; bb2 = bhh[64 + jj];
  }
  __syncthreads();
  for (int t = 0; t < 96; t++) {
    float acc = 0.0f;
#pragma unroll
    for (int k = 0; k < 32; k++) acc = fmaf(hs[b][k], Whs[row][k], acc);
    ga[g][b][j] = acc;
    __syncthreads();
    if (tid < 256) {
      int bb = tid >> 5, jj = tid & 31;
      const float* gp = gi + ((size_t)bb * 96 + t) * 96;
      float gr = ga[0][bb][jj] + bb0;
      float gz = ga[1][bb][jj] + bb1;
      float gn = ga[2][bb][jj] + bb2;
      float r = 1.0f / (1.0f + __expf(-(gp[jj] + gr)));
      float z = 1.0f / (1.0f + __expf(-(gp[32 + jj] + gz)));
      float n = tanhf(gp[64 + jj] + r * gn);
      float hn = (1.0f - z) * n + z * hs[bb][jj];
      hs[bb][jj] = hn;
      X[((size_t)bb * 2096 + 2000 + t) * 32 + jj] = (_Float16)hn;
    }
    __syncthreads();
  }
}

// ---------------- Kernel 4: fused GNN pass (MFMA, f16 X, stride-42 Xq) ----------------
__global__ __launch_bounds__(256) void k_gnn(
    const _Float16* __restrict__ Xa, const _Float16* __restrict__ Xin,
    _Float16* __restrict__ Xout, const float* __restrict__ W,
    const float* __restrict__ bias) {
  __shared__ _Float16 XaR[32][40];
  __shared__ _Float16 Xm[2][64][40];
  __shared__ _Float16 Xq[2][64][42];
  __shared__ _Float16 At[32][72];
  __shared__ float Pm[32][36];
  __shared__ float Ws[32][36];
  __shared__ float bs[32];
  int tid = threadIdx.x;
  int l = tid & 63, w = tid >> 6;
  int b = blockIdx.y;
  int r0 = blockIdx.x * 32;
  const _Float16* Xab = Xa + (size_t)b * 2096 * 32;
  const _Float16* Xib = Xin + (size_t)b * 2096 * 32;
  half8 hz = {(_Float16)0, (_Float16)0, (_Float16)0, (_Float16)0,
              (_Float16)0, (_Float16)0, (_Float16)0, (_Float16)0};

  for (int i = tid; i < 1024; i += 256) Ws[i >> 5][i & 31] = W[i];
  if (tid < 32) bs[tid] = bias[tid];
  if (tid < 128) {
    int r = tid >> 2, k = (tid & 3) * 8;
    half8 v = (r0 + r < 2096)
                  ? *reinterpret_cast<const half8*>(Xab + (size_t)(r0 + r) * 32 + k)
                  : hz;
    *reinterpret_cast<half8*>(&XaR[r][k]) = v;
  }
  int sr = tid >> 2, sk = (tid & 3) * 8;
  {
    *reinterpret_cast<half8*>(&Xm[0][sr][sk]) =
        *reinterpret_cast<const half8*>(Xab + (size_t)sr * 32 + sk);
    half8 vq = *reinterpret_cast<const half8*>(Xib + (size_t)sr * 32 + sk);
    unsigned int u[4];
    __builtin_memcpy(u, &vq, 16);
    unsigned int* qp = (unsigned int*)&Xq[0][sr][sk];
    qp[0] = u[0]; qp[1] = u[1]; qp[2] = u[2]; qp[3] = u[3];
  }
  __syncthreads();

  int lr = l & 15, lk = (l >> 4) * 8, lq = (l >> 4) * 4;
  int smt = w >> 1, snt2 = w & 1;
  int pmt = w >> 1, pnt = w & 1;
  half8 afrag = *reinterpret_cast<const half8*>(&XaR[smt * 16 + lr][lk]);
  f32x4 pacc = {0.f, 0.f, 0.f, 0.f};

  for (int tt = 0; tt < 33; tt++) {
    int cur = tt & 1, nb = cur ^ 1;
    half8 vm = hz, vq = hz;
    bool hv = (tt + 1 < 33);
    if (hv) {
      int gm = (tt + 1) * 64 + sr;
      if (gm < 2096) {
        vm = *reinterpret_cast<const half8*>(Xab + (size_t)gm * 32 + sk);
        vq = *reinterpret_cast<const half8*>(Xib + (size_t)gm * 32 + sk);
      }
    }
#pragma unroll
    for (int n16 = 0; n16 < 2; n16++) {
      int c0 = snt2 * 32 + n16 * 16;
      half8 bfrag = *reinterpret_cast<const half8*>(&Xm[cur][c0 + lr][lk]);
      f32x4 s4 = __builtin_amdgcn_mfma_f32_16x16x32_f16(
          afrag, bfrag, (f32x4){0.f, 0.f, 0.f, 0.f}, 0, 0, 0);
#pragma unroll
      for (int j = 0; j < 4; j++) {
        float e = __expf(-2.0f * fmaxf(s4[j], 0.0f));
        At[smt * 16 + lq + j][c0 + lr] = (_Float16)((1.0f - e) / (1.0f + e));
      }
    }
    __syncthreads();
    {
      int nn = pnt * 16 + lr;
#pragma unroll
      for (int kc = 0; kc < 2; kc++) {
        half8 af = *reinterpret_cast<const half8*>(&At[pmt * 16 + lr][kc * 32 + lk]);
        half8 bf;
        int kb = kc * 32 + lk;
#pragma unroll
        for (int e = 0; e < 8; e++) bf[e] = Xq[cur][kb + e][nn];
        pacc = __builtin_amdgcn_mfma_f32_16x16x32_f16(af, bf, pacc, 0, 0, 0);
      }
    }
    if (hv) {
      *reinterpret_cast<half8*>(&Xm[nb][sr][sk]) = vm;
      unsigned int u[4];
      __builtin_memcpy(u, &vq, 16);
      unsigned int* qp = (unsigned int*)&Xq[nb][sr][sk];
      qp[0] = u[0]; qp[1] = u[1]; qp[2] = u[2]; qp[3] = u[3];
    }
    __syncthreads();
  }

#pragma unroll
  for (int j = 0; j < 4; j++) Pm[pmt * 16 + lq + j][pnt * 16 + lr] = pacc[j];
  __syncthreads();
  int r = tid & 31, fgr = tid >> 5;
  int f0 = fgr * 4;
  float o[4];
#pragma unroll
  for (int j = 0; j < 4; j++) o[j] = bs[f0 + j];
#pragma unroll
  for (int k = 0; k < 32; k++) {
    float mv = Pm[r][k];
    float4 wv = *reinterpret_cast<const float4*>(&Ws[k][f0]);
    o[0] = fmaf(mv, wv.x, o[0]);
    o[1] = fmaf(mv, wv.y, o[1]);
    o[2] = fmaf(mv, wv.z, o[2]);
    o[3] = fmaf(mv, wv.w, o[3]);
  }
  int grr = r0 + r;
  if (grr < 2096) {
    _Float16* dst = Xout + ((size_t)b * 2096 + grr) * 32 + f0;
#pragma unroll
    for (int j = 0; j < 4; j++) {
      float v = o[j];
      dst[j] = (_Float16)(v > 0.0f ? v : (__expf(v) - 1.0f));
    }
  }
}

// ---------------- Kernel 7: fused persistent kernel (GRU + rs + final combine) ----------------
// seq flags stride 32 (per-block private cache line: parallel writer path).
__global__ __launch_bounds__(1024) void k_trgru(
    const _Float16* __restrict__ X, const float* __restrict__ wih,
    const float* __restrict__ bih, float* __restrict__ gi,
    const float* __restrict__ whh, const float* __restrict__ bhh,
    unsigned char* __restrict__ hA, unsigned char* __restrict__ hB,
    float* __restrict__ rt, int* __restrict__ seq,
    const float* __restrict__ frW1, const float* __restrict__ frb1,
    const float* __restrict__ frW2, const float* __restrict__ frb2,
    float* __restrict__ rs, const float* __restrict__ outW,
    const float* __restrict__ outb, float* __restrict__ out) {
  __shared__ __align__(16) unsigned char SM[122880];
  int tid = threadIdx.x;
  int blk = blockIdx.x;

  if (blk >= NBLK) {
    // ================= rs path (spare blocks) =================
    float* W1s = (float*)(SM);
    float* W2s = (float*)(SM + 12288);
    float* b1s = (float*)(SM + 50688);
    float* b2s = (float*)(SM + 51072);
    float* Xt  = (float*)(SM + 51456);
    float* Hl  = (float*)(SM + 55680);
    for (int i = tid; i < 32 * 96; i += 1024) W1s[i] = frW1[i];
    for (int i = tid; i < 96 * 96; i += 1024) W2s[(i / 96) * 100 + (i % 96)] = frW2[i];
    if (tid < 96) { b1s[tid] = frb1[tid]; b2s[tid] = frb2[tid]; }
    __syncthreads();
    for (int ti = blk - NBLK; ti < 504; ti += NBLK) {
      int b = ti / 63, n0 = (ti % 63) * 32;
      {
        int r = tid >> 5, k = tid & 31;
        Xt[r * 33 + k] =
            (n0 + r < 2000) ? (float)X[((size_t)b * 2096 + n0 + r) * 32 + k] : 0.0f;
      }
      __syncthreads();
#pragma unroll
      for (int q = 0; q < 3; q++) {
        int idx = q * 1024 + tid;
        int r = idx / 96, c = idx % 96;
        float a = b1s[c];
#pragma unroll 8
        for (int k = 0; k < 32; k++) a = fmaf(Xt[r * 33 + k], W1s[k * 96 + c], a);
        Hl[r * 100 + c] = a > 0.0f ? a : (__expf(a) - 1.0f);
      }
      __syncthreads();
#pragma unroll
      for (int q = 0; q < 3; q++) {
        int idx = q * 1024 + tid;
        int r = idx / 96, c = idx % 96;
        float o = b2s[c];
#pragma unroll 8
        for (int k = 0; k < 96; k++) o = fmaf(Hl[r * 100 + k], W2s[k * 100 + c], o);
        if (n0 + r < 2000) {
          __hip_atomic_store(&rs[((size_t)b * 2000 + n0 + r) * 96 + c], o,
                             __ATOMIC_RELAXED, __HIP_MEMORY_SCOPE_AGENT);
        }
      }
      __syncthreads();
    }
    if (tid == 0) {
      __hip_atomic_store(&seq[blk * 32], 96, __ATOMIC_RELAXED,
                         __HIP_MEMORY_SCOPE_AGENT);
    }
  } else {
    // ================= GRU path =================
    unsigned char* wf = SM;               // 3*32768
    float* pt = (float*)(SM + 98304);     // 6144 f32
    int l = tid & 63, w = tid >> 6;

    for (int i = tid; i < 12288; i += 1024) ((unsigned long long*)wf)[i] = 0ull;

    // gi prologue: this block's own 48 gate-rows
    if (tid < 768) {
      int t = tid >> 3, b = tid & 7;
      float xr[32];
      const _Float16* xp = X + ((size_t)b * 2096 + 2000 + t) * 32;
#pragma unroll
      for (int k = 0; k < 32; k++) xr[k] = (float)xp[k];
      float* gp = gi + ((size_t)b * 96 + t) * 6000;
      for (int g = 0; g < 3; g++) {
#pragma unroll
        for (int j = 0; j < 16; j++) {
          int row = g * 2000 + blk * 16 + j;
          const float* wr = wih + (size_t)row * 32;
          float a = bih[row];
#pragma unroll 8
          for (int k = 0; k < 32; k++) a = fmaf(xr[k], wr[k], a);
          gp[row] = a;
        }
      }
    }

    // one-time weight fill: f32 -> fp8 e4m3 fragments
    for (int i = tid; i < 3 * 64 * 64; i += 1024) {
      int g = i >> 12;
      int c = (i >> 6) & 63;
      int l2 = i & 63;
      int j = l2 & 15;
      int k0 = c * 32 + ((l2 >> 4) << 3);
      if (k0 <= 1992) {
        const float* src = whh + ((size_t)(g * 2000 + blk * 16 + j)) * 2000 + k0;
        float4 v0 = *reinterpret_cast<const float4*>(src);
        float4 v1 = *reinterpret_cast<const float4*>(src + 4);
        unsigned int lo = __builtin_amdgcn_cvt_pk_fp8_f32(v0.x, v0.y, 0, false);
        lo = __builtin_amdgcn_cvt_pk_fp8_f32(v0.z, v0.w, lo, true);
        unsigned int hi = __builtin_amdgcn_cvt_pk_fp8_f32(v1.x, v1.y, 0, false);
        hi = __builtin_amdgcn_cvt_pk_fp8_f32(v1.z, v1.w, hi, true);
        unsigned long long q = ((unsigned long long)hi << 32) | (unsigned long long)lo;
        *reinterpret_cast<unsigned long long*>(wf + (size_t)g * 32768 + c * 512 + l2 * 8) = q;
      }
    }

    int cj = tid >> 3, cb = tid & 7;
    int jg = blk * 16 + cj;
    float hold = 0.0f, bR = 0.f, bZ = 0.f, bN = 0.f;
    if (tid < 128) {
      bR = bhh[jg]; bZ = bhh[2000 + jg]; bN = bhh[4000 + jg];
    }
    int bb = l & 7, kblk = (l >> 4) * 8;
    __syncthreads();

    // prefetch gi for t=0
    float gir = 0.f, giz = 0.f, gin = 0.f;
    if (tid < 128) {
      const float* gp = gi + ((size_t)cb * 96 + 0) * 6000;
      gir = gp[jg]; giz = gp[2000 + jg]; gin = gp[4000 + jg];
    }

    for (int t = 0; t < 96; t++) {
      const unsigned char* hc = (t & 1) ? hB : hA;
      unsigned char* hn = (t & 1) ? hA : hB;
      f32x4 a0 = {0.f, 0.f, 0.f, 0.f}, a1 = {0.f, 0.f, 0.f, 0.f}, a2 = {0.f, 0.f, 0.f, 0.f};
#pragma unroll
      for (int i = 0; i < 4; i++) {
        int c = w * 4 + i;
        int k0 = c * 32 + kblk;
        long long bv = 0;
        if (k0 <= 1992)
          bv = *reinterpret_cast<const long long*>(hc + bb * 2000 + k0);
        long long w0 = *reinterpret_cast<const long long*>(wf + 0 * 32768 + c * 512 + l * 8);
        long long w1 = *reinterpret_cast<const long long*>(wf + 1 * 32768 + c * 512 + l * 8);
        long long w2 = *reinterpret_cast<const long long*>(wf + 2 * 32768 + c * 512 + l * 8);
        a0 = __builtin_amdgcn_mfma_f32_16x16x32_fp8_fp8(w0, bv, a0, 0, 0, 0);
        a1 = __builtin_amdgcn_mfma_f32_16x16x32_fp8_fp8(w1, bv, a1, 0, 0, 0);
        a2 = __builtin_amdgcn_mfma_f32_16x16x32_fp8_fp8(w2, bv, a2, 0, 0, 0);
      }
      {
        int bcol = l & 15;
        if (bcol < 8) {
          int lb = l >> 4;
          *reinterpret_cast<f32x4*>(pt + w * 384 + 0 * 128 + lb * 32 + bcol * 4) = a0;
          *reinterpret_cast<f32x4*>(pt + w * 384 + 1 * 128 + lb * 32 + bcol * 4) = a1;
          *reinterpret_cast<f32x4*>(pt + w * 384 + 2 * 128 + lb * 32 + bcol * 4) = a2;
        }
      }
      __syncthreads();
      if (tid < 128) {
        float s[3];
#pragma unroll
        for (int g = 0; g < 3; g++) {
          int base = g * 128 + (cj >> 2) * 32 + cb * 4 + (cj & 3);
          float acc = 0.f;
#pragma unroll
          for (int w2 = 0; w2 < 16; w2++) acc += pt[w2 * 384 + base];
          s[g] = acc;
        }
        float r_ = 1.0f / (1.0f + __expf(-(gir + s[0] + bR)));
        float z_ = 1.0f / (1.0f + __expf(-(giz + s[1] + bZ)));
        float n_ = tanhf(gin + r_ * (s[2] + bN));
        hold = (1.0f - z_) * n_ + z_ * hold;
        {
          unsigned int p = __builtin_amdgcn_cvt_pk_fp8_f32(hold, 0.0f, 0, false);
          __hip_atomic_store(hn + cb * 2000 + jg, (unsigned char)(p & 0xFF),
                             __ATOMIC_RELAXED, __HIP_MEMORY_SCOPE_AGENT);
        }
        __hip_atomic_store(&rt[((size_t)cb * 96 + t) * 2000 + jg], hold,
                           __ATOMIC_RELAXED, __HIP_MEMORY_SCOPE_AGENT);
      }
      __syncthreads();  // drains h/rt stores before flag
      if (tid == 0) {
        __hip_atomic_store(&seq[blk * 32], t + 1, __ATOMIC_RELAXED,
                           __HIP_MEMORY_SCOPE_AGENT);
      }
      // prefetch next step's gi while wave 2 polls (overlaps with barrier wait)
      if (tid < 128 && t + 1 < 96) {
        const float* gp = gi + ((size_t)cb * 96 + (t + 1)) * 6000;
        gir = gp[jg]; giz = gp[2000 + jg]; gin = gp[4000 + jg];
      }
      if ((tid >> 6) == 2) {
        int lane = tid & 63;
        const int* s1 = &seq[lane * 32];
        const int* s2 = &seq[((lane + 64) < NBLK ? (lane + 64) : lane) * 32];
        while (true) {
          int v1 = __hip_atomic_load(s1, __ATOMIC_RELAXED, __HIP_MEMORY_SCOPE_AGENT);
          int v2 = __hip_atomic_load(s2, __ATOMIC_RELAXED, __HIP_MEMORY_SCOPE_AGENT);
          if (__all(v1 > t && v2 > t)) break;
          __builtin_amdgcn_s_sleep(1);
        }
        if (lane == 0) {
          (void)__hip_atomic_load(s1, __ATOMIC_ACQUIRE, __HIP_MEMORY_SCOPE_AGENT);
        }
      }
      __syncthreads();
    }
  }

  // ================= shared epilogue: final barrier + out matmul =================
  {
    float* wsm = (float*)SM;
    __syncthreads();
    if (tid >= 128 && tid < 224) wsm[tid - 128] = outW[tid - 128];
    if (tid == 224) wsm[96] = outb[0];
    if (tid < 64) {
      const int* p0 = &seq[tid * 32];
      const int* p1 = &seq[(tid + 64) * 32];
      const int* p2 = &seq[(tid + 128) * 32];
      int i3 = tid + 192; if (i3 >= TOTBLK) i3 = tid;
      const int* p3 = &seq[i3 * 32];
      while (true) {
        int v0 = __hip_atomic_load(p0, __ATOMIC_RELAXED, __HIP_MEMORY_SCOPE_AGENT);
        int v1 = __hip_atomic_load(p1, __ATOMIC_RELAXED, __HIP_MEMORY_SCOPE_AGENT);
        int v2 = __hip_atomic_load(p2, __ATOMIC_RELAXED, __HIP_MEMORY_SCOPE_AGENT);
        int v3 = __hip_atomic_load(p3, __ATOMIC_RELAXED, __HIP_MEMORY_SCOPE_AGENT);
        if (__all(v0 >= 96 && v1 >= 96 && v2 >= 96 && v3 >= 96)) break;
        __builtin_amdgcn_s_sleep(2);
      }
      if (tid == 0) {
        (void)__hip_atomic_load(p0, __ATOMIC_ACQUIRE, __HIP_MEMORY_SCOPE_AGENT);
      }
    }
    __syncthreads();
    if (tid < 64) {
      int idx = blk * 64 + tid;
      int b = idx / 2000, n = idx % 2000;
      const float* rsp = rs + (size_t)idx * 96;
      float acc = wsm[96];
      for (int t4 = 0; t4 < 24; t4++) {
        float4 rv = *reinterpret_cast<const float4*>(rsp + t4 * 4);
        int t = t4 * 4;
        acc = fmaf(rv.x + rt[((size_t)b * 96 + t + 0) * 2000 + n], wsm[t + 0], acc);
        acc = fmaf(rv.y + rt[((size_t)b * 96 + t + 1) * 2000 + n], wsm[t + 1], acc);
        acc = fmaf(rv.z + rt[((size_t)b * 96 + t + 2) * 2000 + n], wsm[t + 2], acc);
        acc = fmaf(rv.w + rt[((size_t)b * 96 + t + 3) * 2000 + n], wsm[t + 3], acc);
      }
      out[idx] = acc;
    }
  }
}

extern "C" void kernel_launch(void* const* d_in, const int* in_sizes, int n_in,
                              void* d_out, int out_size, void* d_ws, size_t ws_size,
                              hipStream_t stream) {
  const float* x      = (const float*)d_in[0];
  const float* x_mark = (const float*)d_in[1];
  const float* sp_emb = (const float*)d_in[2];
  const float* sp_W1  = (const float*)d_in[3];
  const float* sp_b1  = (const float*)d_in[4];
  const float* sp_W2  = (const float*)d_in[5];
  const float* sp_b2  = (const float*)d_in[6];
  const float* t_emb  = (const float*)d_in[7];
  const float* t_Wih  = (const float*)d_in[8];
  const float* t_Whh  = (const float*)d_in[9];
  const float* t_bih  = (const float*)d_in[10];
  const float* t_bhh  = (const float*)d_in[11];
  const float* gcn_W  = (const float*)d_in[12];
  const float* gcn_b  = (const float*)d_in[13];
  const float* fr_W1  = (const float*)d_in[14];
  const float* fr_b1  = (const float*)d_in[15];
  const float* fr_W2  = (const float*)d_in[16];
  const float* fr_b2  = (const float*)d_in[17];
  const float* tr_Wih = (const float*)d_in[18];
  const float* tr_Whh = (const float*)d_in[19];
  const float* tr_bih = (const float*)d_in[20];
  const float* tr_bhh = (const float*)d_in[21];
  const float* out_W  = (const float*)d_in[22];
  const float* out_b  = (const float*)d_in[23];
  (void)in_sizes; (void)n_in; (void)out_size; (void)ws_size;

  float* ws = (float*)d_ws;
  float* X0   = ws;
  float* X1   = X0 + 536576;
  float* X2   = X1 + 536576;
  float* tgi  = X2 + 536576;           // 768*96
  float* trgi = tgi + 73728;           // 8*96*6000
  float* hsl  = trgi + 4608000;        // hA/hB (fp8, 16000 B each)
  float* rt   = hsl + 16000;           // 8*96*2000
  float* rs   = rt + 1536000;          // 8*2000*96
  float* barf = rs + 1536000;          // BAR_INTS ints (seq)

  _Float16* X0h = (_Float16*)X0;
  _Float16* X1h = (_Float16*)X1;
  _Float16* X2h = (_Float16*)X2;
  unsigned char* hA = (unsigned char*)hsl;
  unsigned char* hB = hA + 16000;
  int* seq = (int*)barf;

  k_pre<<<159, 256, 0, stream>>>(x, x_mark, sp_emb, sp_W1, sp_b1, sp_W2, sp_b2,
                                 t_emb, t_Wih, t_bih, X0h, tgi, seq, hA);
  k_tgru<<<1, 768, 0, stream>>>(tgi, t_Whh, t_bhh, X0h);

  dim3 gg(66, 8);
  k_gnn<<<gg, 256, 0, stream>>>(X0h, X0h, X1h, gcn_W + 0 * 1024, gcn_b + 0 * 32);
  k_gnn<<<gg, 256, 0, stream>>>(X0h, X1h, X2h, gcn_W + 1 * 1024, gcn_b + 1 * 32);
  k_gnn<<<gg, 256, 0, stream>>>(X2h, X2h, X0h, gcn_W + 2 * 1024, gcn_b + 2 * 32);
  k_gnn<<<gg, 256, 0, stream>>>(X2h, X0h, X1h, gcn_W + 3 * 1024, gcn_b + 3 * 32);

  {
    const _Float16* a0 = X1h;
    const float* a1 = tr_Wih;
    const float* a2 = tr_bih;
    float* a3 = trgi;
    const float* a4 = tr_Whh;
    const float* a5 = tr_bhh;
    unsigned char* a6 = hA;
    unsigned char* a7 = hB;
    float* a8 = rt;
    int* a9 = seq;
    const float* a10 = fr_W1;
    const float* a11 = fr_b1;
    const float* a12 = fr_W2;
    const float* a13 = fr_b2;
    float* a14 = rs;
    const float* a15 = out_W;
    const float* a16 = out_b;
    float* a17 = (float*)d_out;
    void* cargs[] = {&a0, &a1, &a2, &a3, &a4, &a5, &a6, &a7, &a8, &a9,
                     &a10, &a11, &a12, &a13, &a14, &a15, &a16, &a17};
    hipLaunchCooperativeKernel((const void*)k_trgru, dim3(TOTBLK), dim3(1024), cargs, 0, stream);
  }
}